// Round 2
// baseline (816.661 us; speedup 1.0000x reference)
//
#include <hip/hip_runtime.h>
#include <math.h>

#define NK 6
#define NB 8
#define NT 12
#define D 256      // DIM == HALF == 256
#define NG 8       // offset groups == sampling points
#define NHD 8      // num heads
#define HW 256     // HBEV == WBEV
#define NQ (NK*NB*NT)   // 576 queries

__global__ __launch_bounds__(256)
void dca_kernel(const float* __restrict__ dec_embed,
                const float* __restrict__ bev_feat,
                const float* __restrict__ query_scale,
                const float* __restrict__ ref_points,
                const float* __restrict__ Wq,     const float* __restrict__ bq,
                const float* __restrict__ Wk,     const float* __restrict__ Wv,
                const float* __restrict__ pq_W1,  const float* __restrict__ pq_b1,
                const float* __restrict__ pq_W2,  const float* __restrict__ pq_b2,
                const float* __restrict__ pk_W1,  const float* __restrict__ pk_b1,
                const float* __restrict__ pk_W2,  const float* __restrict__ pk_b2,
                const float* __restrict__ off_W1, const float* __restrict__ off_b1,
                const float* __restrict__ off_W2, const float* __restrict__ off_b2,
                const float* __restrict__ out_W,  const float* __restrict__ out_b,
                float* __restrict__ out)
{
    __shared__ float de[D];
    __shared__ float conq[D];
    __shared__ float qse[D];
    __shared__ float tmp1[D];
    __shared__ float posq[D];
    __shared__ float oatt[D];
    __shared__ float h1[NG][64];
    __shared__ float gxy[NG][2];     // vgrid_scaled per group (x,y)
    __shared__ float samp[NG][D];    // bilinear-sampled bev features
    __shared__ float conk[NG][D];
    __shared__ float vmat[NG][D];
    __shared__ float kse[NG][D];
    __shared__ float tmpk[NG][D];
    __shared__ float posk[NG][D];
    __shared__ float sim[NHD][NG];

    const int tid = threadIdx.x;
    const int q   = blockIdx.x;              // flattened (k,b,t) in (K,B,T) order
    const int bb  = (q / NT) % NB;           // batch index

    const float NORM = 0.01953125f;          // 2/102.4
    const float TWO_PI = 6.28318530717958647692f;
    const float L2_40_OVER_64 = 5.32192809488736234787f / 64.0f;  // log2(40)/64

    // ---- stage 1: load dec_embed row ----
    de[tid] = dec_embed[(size_t)q * D + tid];
    __syncthreads();

    // ---- stage 2: con_q = de @ Wq + bq ----
    {
        float acc = bq[tid];
        for (int i = 0; i < D; ++i) acc += de[i] * Wq[i * D + tid];
        conq[tid] = acc;
    }
    __syncthreads();

    // ---- stage 3: offset MLP layer 1 (per group, 32 -> 64, exact GELU) ----
    for (int idx = tid; idx < NG * 64; idx += 256) {
        int g = idx >> 6, j = idx & 63;
        float acc = off_b1[j];
        for (int i = 0; i < 32; ++i) acc += conq[g * 32 + i] * off_W1[i * 64 + j];
        h1[g][j] = 0.5f * acc * (1.0f + erff(acc * 0.70710678118654752440f));
    }
    __syncthreads();

    // ---- stage 4: offset MLP layer 2 (64 -> 2), tanh*4, add ref point, normalize ----
    if (tid < NG * 2) {
        int g = tid >> 1, c = tid & 1;
        float acc = off_b2[c];
        for (int j = 0; j < 64; ++j) acc += h1[g][j] * off_W2[j * 2 + c];
        float off = tanhf(acc) * 4.0f;
        float rp  = ref_points[(size_t)q * 2 + c];
        gxy[g][c] = (rp + off) * NORM;
    }
    __syncthreads();

    // ---- stage 5: bilinear sampling of bev_feat (zeros padding, align_corners=False)
    //               + sine embeds (qse for ref point, kse per group) ----
    {
        const float* bevb = bev_feat + (size_t)bb * D * HW * HW;
        const int c = tid;
        const float* ch = bevb + (size_t)c * HW * HW;
        for (int g = 0; g < NG; ++g) {
            float gx = gxy[g][0], gy = gxy[g][1];
            float ix = ((gx + 1.0f) * HW - 1.0f) * 0.5f;
            float iy = ((gy + 1.0f) * HW - 1.0f) * 0.5f;
            float fx0 = floorf(ix), fy0 = floorf(iy);
            float wx = ix - fx0, wy = iy - fy0;
            int x0 = (int)fx0, y0 = (int)fy0;
            bool xin0 = (x0 >= 0) && (x0 < HW);
            bool xin1 = (x0 + 1 >= 0) && (x0 + 1 < HW);
            bool yin0 = (y0 >= 0) && (y0 < HW);
            bool yin1 = (y0 + 1 >= 0) && (y0 + 1 < HW);
            float v00 = 0.f, v01 = 0.f, v10 = 0.f, v11 = 0.f;
            if (yin0) {
                if (xin0) v00 = ch[y0 * HW + x0];
                if (xin1) v01 = ch[y0 * HW + x0 + 1];
            }
            if (yin1) {
                if (xin0) v10 = ch[(y0 + 1) * HW + x0];
                if (xin1) v11 = ch[(y0 + 1) * HW + x0 + 1];
            }
            samp[g][c] = v00 * (1.f - wx) * (1.f - wy) + v01 * wx * (1.f - wy)
                       + v10 * (1.f - wx) * wy        + v11 * wx * wy;
        }
        // qse: sine embed of ref_scaled.  layout: [0:128) from y, [128:256) from x
        {
            float rx = ref_points[(size_t)q * 2 + 0] * NORM;
            float ry = ref_points[(size_t)q * 2 + 1] * NORM;
            int j = tid;
            float pos = (j < 128) ? ry : rx;
            int m = (j & 127) >> 1;
            float freq = TWO_PI / exp2f((float)m * L2_40_OVER_64);
            float e = pos * freq;
            qse[j] = (j & 1) ? cosf(e) : sinf(e);
        }
        // kse per group
        for (int g = 0; g < NG; ++g) {
            int j = tid;
            float pos = (j < 128) ? gxy[g][1] : gxy[g][0];
            int m = (j & 127) >> 1;
            float freq = TWO_PI / exp2f((float)m * L2_40_OVER_64);
            float e = pos * freq;
            kse[g][j] = (j & 1) ? cosf(e) : sinf(e);
        }
    }
    __syncthreads();

    // ---- stage 6: con_k = samp @ Wk, v = samp @ Wv (grouped, weights read once);
    //               pos-q layer1; pos-k layer1 (grouped) ----
    {
        float accK[NG], accV[NG];
        #pragma unroll
        for (int g = 0; g < NG; ++g) { accK[g] = 0.f; accV[g] = 0.f; }
        for (int i = 0; i < D; ++i) {
            float wk = Wk[i * D + tid];
            float wv = Wv[i * D + tid];
            #pragma unroll
            for (int g = 0; g < NG; ++g) {
                float s = samp[g][i];
                accK[g] += s * wk;
                accV[g] += s * wv;
            }
        }
        #pragma unroll
        for (int g = 0; g < NG; ++g) { conk[g][tid] = accK[g]; vmat[g][tid] = accV[g]; }
    }
    {
        float acc = pq_b1[tid];
        for (int i = 0; i < D; ++i) acc += qse[i] * pq_W1[i * D + tid];
        tmp1[tid] = fmaxf(acc, 0.f);
    }
    {
        float acc[NG];
        float bias = pk_b1[tid];
        #pragma unroll
        for (int g = 0; g < NG; ++g) acc[g] = bias;
        for (int i = 0; i < D; ++i) {
            float w = pk_W1[i * D + tid];
            #pragma unroll
            for (int g = 0; g < NG; ++g) acc[g] += kse[g][i] * w;
        }
        #pragma unroll
        for (int g = 0; g < NG; ++g) tmpk[g][tid] = fmaxf(acc[g], 0.f);
    }
    __syncthreads();

    // ---- stage 7: pos-q layer2 (*query_scale), pos-k layer2 ----
    {
        float acc = pq_b2[tid];
        for (int i = 0; i < D; ++i) acc += tmp1[i] * pq_W2[i * D + tid];
        posq[tid] = acc * query_scale[(size_t)q * D + tid];
    }
    {
        float acc[NG];
        float bias = pk_b2[tid];
        #pragma unroll
        for (int g = 0; g < NG; ++g) acc[g] = bias;
        for (int i = 0; i < D; ++i) {
            float w = pk_W2[i * D + tid];
            #pragma unroll
            for (int g = 0; g < NG; ++g) acc[g] += tmpk[g][i] * w;
        }
        #pragma unroll
        for (int g = 0; g < NG; ++g) posk[g][tid] = acc[g];
    }
    __syncthreads();

    // ---- stage 8: sim[h][g] = (q . k) * SCALE ----
    if (tid < NHD * NG) {
        int h = tid >> 3, g = tid & 7;
        float s = 0.f;
        for (int d = 0; d < 32; ++d) {
            s += conq[h * 32 + d] * conk[g][h * 32 + d];
            s += posq[h * 32 + d] * posk[g][h * 32 + d];
        }
        sim[h][g] = s * 0.125f;   // SCALE = 64^-0.5
    }
    __syncthreads();

    // ---- stage 9: softmax over g ----
    if (tid < NHD) {
        int h = tid;
        float mx = sim[h][0];
        for (int g = 1; g < NG; ++g) mx = fmaxf(mx, sim[h][g]);
        float ex[NG], sum = 0.f;
        for (int g = 0; g < NG; ++g) { ex[g] = expf(sim[h][g] - mx); sum += ex[g]; }
        float inv = 1.0f / sum;
        for (int g = 0; g < NG; ++g) sim[h][g] = ex[g] * inv;
    }
    __syncthreads();

    // ---- stage 10: attention output (head-major, 8 heads x 32 dims) ----
    {
        int h = tid >> 5, d = tid & 31;
        float o = 0.f;
        #pragma unroll
        for (int g = 0; g < NG; ++g) o += sim[h][g] * vmat[g][h * 32 + d];
        oatt[tid] = o;
    }
    __syncthreads();

    // ---- stage 11: out = oatt @ out_W + out_b + dec_embed ----
    {
        float acc = out_b[tid];
        for (int i = 0; i < D; ++i) acc += oatt[i] * out_W[i * D + tid];
        out[(size_t)q * D + tid] = acc + de[tid];
    }
}

extern "C" void kernel_launch(void* const* d_in, const int* in_sizes, int n_in,
                              void* d_out, int out_size, void* d_ws, size_t ws_size,
                              hipStream_t stream) {
    const float* dec_embed   = (const float*)d_in[0];
    const float* bev_feat    = (const float*)d_in[1];
    const float* query_scale = (const float*)d_in[2];
    const float* ref_points  = (const float*)d_in[3];
    const float* Wq     = (const float*)d_in[4];
    const float* bq     = (const float*)d_in[5];
    const float* Wk     = (const float*)d_in[6];
    const float* Wv     = (const float*)d_in[7];
    const float* pq_W1  = (const float*)d_in[8];
    const float* pq_b1  = (const float*)d_in[9];
    const float* pq_W2  = (const float*)d_in[10];
    const float* pq_b2  = (const float*)d_in[11];
    const float* pk_W1  = (const float*)d_in[12];
    const float* pk_b1  = (const float*)d_in[13];
    const float* pk_W2  = (const float*)d_in[14];
    const float* pk_b2  = (const float*)d_in[15];
    const float* off_W1 = (const float*)d_in[16];
    const float* off_b1 = (const float*)d_in[17];
    const float* off_W2 = (const float*)d_in[18];
    const float* off_b2 = (const float*)d_in[19];
    const float* out_W  = (const float*)d_in[20];
    const float* out_b  = (const float*)d_in[21];
    float* out = (float*)d_out;

    dca_kernel<<<NQ, 256, 0, stream>>>(dec_embed, bev_feat, query_scale, ref_points,
                                       Wq, bq, Wk, Wv,
                                       pq_W1, pq_b1, pq_W2, pq_b2,
                                       pk_W1, pk_b1, pk_W2, pk_b2,
                                       off_W1, off_b1, off_W2, off_b2,
                                       out_W, out_b, out);
}

// Round 3
// 761.844 us; speedup vs baseline: 1.0720x; 1.0720x over previous
//
#include <hip/hip_runtime.h>
#include <math.h>

#define NK 6
#define NB 8
#define NT 12
#define D 256      // DIM == HALF == 256
#define NG 8       // offset groups == sampling points
#define NHD 8      // num heads
#define HW 256     // HBEV == WBEV
#define NQ (NK*NB*NT)   // 576 queries

__global__ __launch_bounds__(256)
void dca_kernel(const float* __restrict__ dec_embed,
                const float* __restrict__ bev_feat,
                const float* __restrict__ query_scale,
                const float* __restrict__ ref_points,
                const float* __restrict__ Wq,     const float* __restrict__ bq,
                const float* __restrict__ Wk,     const float* __restrict__ Wv,
                const float* __restrict__ pq_W1,  const float* __restrict__ pq_b1,
                const float* __restrict__ pq_W2,  const float* __restrict__ pq_b2,
                const float* __restrict__ pk_W1,  const float* __restrict__ pk_b1,
                const float* __restrict__ pk_W2,  const float* __restrict__ pk_b2,
                const float* __restrict__ off_W1, const float* __restrict__ off_b1,
                const float* __restrict__ off_W2, const float* __restrict__ off_b2,
                const float* __restrict__ out_W,  const float* __restrict__ out_b,
                float* __restrict__ out)
{
    __shared__ float de[D];
    __shared__ float conq[D];
    __shared__ float qse[D];
    __shared__ float tmp1[D];
    __shared__ float posq[D];
    __shared__ float oatt[D];
    __shared__ float h1[NG][64];
    __shared__ float gxy[NG][2];
    __shared__ float sim[NHD][NG];
    // aliased buffers: bufA = samp (st.5-6) then tmpk (st.6-7)
    //                  bufB = kse  (st.5-6) then posk (st.7-10)
    __shared__ float bufA[NG][D];
    __shared__ float bufB[NG][D];
    __shared__ float conk[NG][D];
    __shared__ float vmat[NG][D];

    const int tid = threadIdx.x;
    const int q   = blockIdx.x;              // flattened (k,b,t) in (K,B,T) order
    const int bb  = (q / NT) % NB;           // batch index

    const float NORM = 0.01953125f;          // 2/102.4
    const float TWO_PI = 6.28318530717958647692f;
    const float L2_40_OVER_64 = 5.32192809488736234787f / 64.0f;  // log2(40)/64

    // ---- stage 1: load dec_embed row ----
    de[tid] = dec_embed[(size_t)q * D + tid];
    __syncthreads();

    // ---- stage 2: con_q = de @ Wq + bq ----
    {
        float acc = bq[tid];
        #pragma unroll 8
        for (int i = 0; i < D; ++i) acc += de[i] * Wq[i * D + tid];
        conq[tid] = acc;
    }
    __syncthreads();

    // ---- stage 3: offset MLP layer 1 (per group, 32 -> 64, exact GELU) ----
    for (int idx = tid; idx < NG * 64; idx += 256) {
        int g = idx >> 6, j = idx & 63;
        float acc = off_b1[j];
        #pragma unroll 8
        for (int i = 0; i < 32; ++i) acc += conq[g * 32 + i] * off_W1[i * 64 + j];
        h1[g][j] = 0.5f * acc * (1.0f + erff(acc * 0.70710678118654752440f));
    }
    __syncthreads();

    // ---- stage 4: offset MLP layer 2 (64 -> 2), tanh*4, add ref point, normalize ----
    if (tid < NG * 2) {
        int g = tid >> 1, c = tid & 1;
        float acc = off_b2[c];
        #pragma unroll 8
        for (int j = 0; j < 64; ++j) acc += h1[g][j] * off_W2[j * 2 + c];
        float off = tanhf(acc) * 4.0f;
        float rp  = ref_points[(size_t)q * 2 + c];
        gxy[g][c] = (rp + off) * NORM;
    }
    __syncthreads();

    // ---- stage 5: bilinear sampling (zeros pad, align_corners=False) + sine embeds ----
    {
        const float* bevb = bev_feat + (size_t)bb * D * HW * HW;
        const int c = tid;
        const float* ch = bevb + (size_t)c * HW * HW;
        #pragma unroll
        for (int g = 0; g < NG; ++g) {
            float gx = gxy[g][0], gy = gxy[g][1];
            float ix = ((gx + 1.0f) * HW - 1.0f) * 0.5f;
            float iy = ((gy + 1.0f) * HW - 1.0f) * 0.5f;
            float fx0 = floorf(ix), fy0 = floorf(iy);
            float wx = ix - fx0, wy = iy - fy0;
            int x0 = (int)fx0, y0 = (int)fy0;
            bool xin0 = (x0 >= 0) && (x0 < HW);
            bool xin1 = (x0 + 1 >= 0) && (x0 + 1 < HW);
            bool yin0 = (y0 >= 0) && (y0 < HW);
            bool yin1 = (y0 + 1 >= 0) && (y0 + 1 < HW);
            float v00 = 0.f, v01 = 0.f, v10 = 0.f, v11 = 0.f;
            if (yin0) {
                if (xin0) v00 = ch[y0 * HW + x0];
                if (xin1) v01 = ch[y0 * HW + x0 + 1];
            }
            if (yin1) {
                if (xin0) v10 = ch[(y0 + 1) * HW + x0];
                if (xin1) v11 = ch[(y0 + 1) * HW + x0 + 1];
            }
            bufA[g][c] = v00 * (1.f - wx) * (1.f - wy) + v01 * wx * (1.f - wy)
                       + v10 * (1.f - wx) * wy        + v11 * wx * wy;   // samp
        }
        // qse: sine embed of ref_scaled.  [0:128) from y, [128:256) from x
        {
            float rx = ref_points[(size_t)q * 2 + 0] * NORM;
            float ry = ref_points[(size_t)q * 2 + 1] * NORM;
            int j = tid;
            float pos = (j < 128) ? ry : rx;
            int m = (j & 127) >> 1;
            float freq = TWO_PI / exp2f((float)m * L2_40_OVER_64);
            float e = pos * freq;
            qse[j] = (j & 1) ? cosf(e) : sinf(e);
        }
        // kse per group
        #pragma unroll
        for (int g = 0; g < NG; ++g) {
            int j = tid;
            float pos = (j < 128) ? gxy[g][1] : gxy[g][0];
            int m = (j & 127) >> 1;
            float freq = TWO_PI / exp2f((float)m * L2_40_OVER_64);
            float e = pos * freq;
            bufB[g][j] = (j & 1) ? cosf(e) : sinf(e);   // kse
        }
    }
    __syncthreads();

    // ---- stage 6a: con_k = samp @ Wk, v = samp @ Wv (grouped, weights read once) ----
    {
        float accK[NG], accV[NG];
        #pragma unroll
        for (int g = 0; g < NG; ++g) { accK[g] = 0.f; accV[g] = 0.f; }
        #pragma unroll 4
        for (int i = 0; i < D; ++i) {
            float wk = Wk[i * D + tid];
            float wv = Wv[i * D + tid];
            #pragma unroll
            for (int g = 0; g < NG; ++g) {
                float s = bufA[g][i];   // samp
                accK[g] += s * wk;
                accV[g] += s * wv;
            }
        }
        #pragma unroll
        for (int g = 0; g < NG; ++g) { conk[g][tid] = accK[g]; vmat[g][tid] = accV[g]; }
    }
    __syncthreads();   // all samp reads done before bufA is re-used as tmpk

    // ---- stage 6b: merged pos-q layer1 + pos-k layer1 (9 accumulators) ----
    {
        float acc[NG + 1];
        float biask = pk_b1[tid];
        #pragma unroll
        for (int g = 0; g < NG; ++g) acc[g] = biask;
        acc[NG] = pq_b1[tid];
        #pragma unroll 4
        for (int i = 0; i < D; ++i) {
            float wk1 = pk_W1[i * D + tid];
            float wq1 = pq_W1[i * D + tid];
            #pragma unroll
            for (int g = 0; g < NG; ++g) acc[g] += bufB[g][i] * wk1;  // kse
            acc[NG] += qse[i] * wq1;
        }
        #pragma unroll
        for (int g = 0; g < NG; ++g) bufA[g][tid] = fmaxf(acc[g], 0.f);  // tmpk
        tmp1[tid] = fmaxf(acc[NG], 0.f);
    }
    __syncthreads();

    // ---- stage 7: merged pos-q layer2 (*query_scale) + pos-k layer2 ----
    {
        float acc[NG + 1];
        float biask = pk_b2[tid];
        #pragma unroll
        for (int g = 0; g < NG; ++g) acc[g] = biask;
        acc[NG] = pq_b2[tid];
        #pragma unroll 4
        for (int i = 0; i < D; ++i) {
            float wk2 = pk_W2[i * D + tid];
            float wq2 = pq_W2[i * D + tid];
            #pragma unroll
            for (int g = 0; g < NG; ++g) acc[g] += bufA[g][i] * wk2;  // tmpk
            acc[NG] += tmp1[i] * wq2;
        }
        #pragma unroll
        for (int g = 0; g < NG; ++g) bufB[g][tid] = acc[g];           // posk
        posq[tid] = acc[NG] * query_scale[(size_t)q * D + tid];
    }
    __syncthreads();

    // ---- stage 8: sim[h][g] = (q . k) * SCALE ----
    if (tid < NHD * NG) {
        int h = tid >> 3, g = tid & 7;
        float s = 0.f;
        #pragma unroll 8
        for (int d = 0; d < 32; ++d) {
            s += conq[h * 32 + d] * conk[g][h * 32 + d];
            s += posq[h * 32 + d] * bufB[g][h * 32 + d];   // posk
        }
        sim[h][g] = s * 0.125f;   // SCALE = 64^-0.5
    }
    __syncthreads();

    // ---- stage 9: softmax over g ----
    if (tid < NHD) {
        int h = tid;
        float mx = sim[h][0];
        for (int g = 1; g < NG; ++g) mx = fmaxf(mx, sim[h][g]);
        float ex[NG], sum = 0.f;
        #pragma unroll
        for (int g = 0; g < NG; ++g) { ex[g] = expf(sim[h][g] - mx); sum += ex[g]; }
        float inv = 1.0f / sum;
        #pragma unroll
        for (int g = 0; g < NG; ++g) sim[h][g] = ex[g] * inv;
    }
    __syncthreads();

    // ---- stage 10: attention output (head-major, 8 heads x 32 dims) ----
    {
        int h = tid >> 5, d = tid & 31;
        float o = 0.f;
        #pragma unroll
        for (int g = 0; g < NG; ++g) o += sim[h][g] * vmat[g][h * 32 + d];
        oatt[tid] = o;
    }
    __syncthreads();

    // ---- stage 11: out = oatt @ out_W + out_b + dec_embed ----
    {
        float acc = out_b[tid];
        #pragma unroll 8
        for (int i = 0; i < D; ++i) acc += oatt[i] * out_W[i * D + tid];
        out[(size_t)q * D + tid] = acc + de[tid];
    }
}

extern "C" void kernel_launch(void* const* d_in, const int* in_sizes, int n_in,
                              void* d_out, int out_size, void* d_ws, size_t ws_size,
                              hipStream_t stream) {
    const float* dec_embed   = (const float*)d_in[0];
    const float* bev_feat    = (const float*)d_in[1];
    const float* query_scale = (const float*)d_in[2];
    const float* ref_points  = (const float*)d_in[3];
    const float* Wq     = (const float*)d_in[4];
    const float* bq     = (const float*)d_in[5];
    const float* Wk     = (const float*)d_in[6];
    const float* Wv     = (const float*)d_in[7];
    const float* pq_W1  = (const float*)d_in[8];
    const float* pq_b1  = (const float*)d_in[9];
    const float* pq_W2  = (const float*)d_in[10];
    const float* pq_b2  = (const float*)d_in[11];
    const float* pk_W1  = (const float*)d_in[12];
    const float* pk_b1  = (const float*)d_in[13];
    const float* pk_W2  = (const float*)d_in[14];
    const float* pk_b2  = (const float*)d_in[15];
    const float* off_W1 = (const float*)d_in[16];
    const float* off_b1 = (const float*)d_in[17];
    const float* off_W2 = (const float*)d_in[18];
    const float* off_b2 = (const float*)d_in[19];
    const float* out_W  = (const float*)d_in[20];
    const float* out_b  = (const float*)d_in[21];
    float* out = (float*)d_out;

    dca_kernel<<<NQ, 256, 0, stream>>>(dec_embed, bev_feat, query_scale, ref_points,
                                       Wq, bq, Wk, Wv,
                                       pq_W1, pq_b1, pq_W2, pq_b2,
                                       pk_W1, pk_b1, pk_W2, pk_b2,
                                       off_W1, off_b1, off_W2, off_b2,
                                       out_W, out_b, out);
}